// Round 7
// baseline (146.349 us; speedup 1.0000x reference)
//
#include <hip/hip_runtime.h>

namespace {
constexpr float SCALE = 0.17677669529663687f; // 32^-0.5
constexpr int CHP = 194; // LDS ch-plane stride; 4*CHP mod 32 = 8 -> with the
                         // lane remap below, every quarter-wave b64 tap read
                         // tiles all 32 banks exactly (conflict-free).

// Block = (image b, head, row h). Stage k/v rows {h-2,h,h+2} x 32 ch into LDS
// once; serve the 9-tap reuse from LDS (b64 = 2 px via even dilation).
// Lane remap: cg bits at lane{0,1,4}, lp bits at lane{2,3,5} ->
// quarter-wave = (cg mod 4) x (lp mod 4): tap bank = 8*cg01 + 2*lp01 + C
// covers all 16 even bank-pairs once -> no b64 read conflicts.
__global__ __launch_bounds__(256, 2) void dilate_attn(
    const float* __restrict__ q, const float* __restrict__ k,
    const float* __restrict__ v, float* __restrict__ out) {
  __shared__ float kbuf[32 * CHP];   // 24832 B
  __shared__ float vbuf[32 * CHP];   // 24832 B

  const int tid = threadIdx.x;
  const int cg  = (tid & 3) | ((tid >> 2) & 4);          // bits 0,1,4
  const int lp  = ((tid >> 2) & 3) | ((tid >> 3) & 4);   // bits 2,3,5
  const int wv  = tid >> 6;
  const int pp  = (wv << 3) | lp;    // pixel pair 0..31 (px0 = 2*pp)

  // XCD swizzle: blk&7 -> XCD; each XCD owns 8 (b,head) combos with rows in
  // order, so the 3x row-halo re-reads hit that XCD's L2.
  const int blk   = blockIdx.x;
  const int s     = blk >> 3;
  const int combo = ((blk & 7) << 3) | (s >> 6);  // 0..63
  const int h     = s & 63;
  const int b     = combo >> 2;
  const int head  = combo & 3;

  const size_t cb = ((size_t)b * 128 + head * 32) * 4096;
  const float* kp = k + cb;
  const float* vp = v + cb;

  // clamped rows + row masks (block-uniform)
  int rows[3]; float rowm[3];
  #pragma unroll
  for (int r = 0; r < 3; ++r) {
    const int ry = h + 2 * (r - 1);
    const bool ok = (unsigned)ry < 64u;
    rows[r] = (ok ? ry : h) * 64;
    rowm[r] = ok ? 1.0f : 0.0f;
  }

  // ---- q loads (independent of staging; overlap with it) ----
  const int px0 = pp << 1;
  float2 q2[4];
  #pragma unroll
  for (int ci = 0; ci < 4; ++ci)
    q2[ci] = *(const float2*)(q + cb + (cg * 4 + ci) * 4096 + h * 64 + px0);

  // ---- stage k,v at float2 granularity: 32 ch x 3 rows x 32 f2 = 3072 f2 ----
  // 16 consecutive lanes sweep p2 = 2*(0..15)*... -> banks 0..31 exactly once
  // per quarter-wave: conflict-free b64 writes. Global: dwordx2, contiguous.
  #pragma unroll
  for (int t = 0; t < 12; ++t) {
    const int l2  = t * 256 + tid;     // f2 index 0..3071
    const int ch  = l2 / 96;           // 96 f2 per channel (3 rows x 32)
    const int rem = l2 - ch * 96;
    const int r   = rem >> 5;
    const int p2  = (rem & 31) << 1;
    const int go  = ch * 4096 + rows[r] + p2;
    const int wo  = ch * CHP + r * 64 + p2;   // even -> 8B aligned
    *(float2*)(kbuf + wo) = *(const float2*)(kp + go);
    *(float2*)(vbuf + wo) = *(const float2*)(vp + go);
  }

  __syncthreads();

  // column taps (clamped, even -> 8B aligned) + x masks (same for both px)
  const int   txL = (pp == 0)  ? 0  : px0 - 2;
  const int   txC = px0;
  const int   txR = (pp == 31) ? 62 : px0 + 2;
  const float mL  = (pp == 0)  ? 0.0f : 1.0f;
  const float mR  = (pp == 31) ? 0.0f : 1.0f;

  // ---- Phase 1: partial logits over this thread's 4 channels ----
  float l0[9], l1[9];
  #pragma unroll
  for (int t = 0; t < 9; ++t) { l0[t] = 0.0f; l1[t] = 0.0f; }

  #pragma unroll
  for (int r = 0; r < 3; ++r) {
    #pragma unroll
    for (int ci = 0; ci < 4; ++ci) {
      const float* kc = kbuf + (cg * 4 + ci) * CHP + r * 64;
      const float2 kL = *(const float2*)(kc + txL);
      const float2 kC = *(const float2*)(kc + txC);
      const float2 kR = *(const float2*)(kc + txR);
      const float2 qq = q2[ci];
      l0[r*3+0] = fmaf(qq.x, kL.x, l0[r*3+0]);
      l1[r*3+0] = fmaf(qq.y, kL.y, l1[r*3+0]);
      l0[r*3+1] = fmaf(qq.x, kC.x, l0[r*3+1]);
      l1[r*3+1] = fmaf(qq.y, kC.y, l1[r*3+1]);
      l0[r*3+2] = fmaf(qq.x, kR.x, l0[r*3+2]);
      l1[r*3+2] = fmaf(qq.y, kR.y, l1[r*3+2]);
    }
  }

  // combine the 8 cg-partials: cg bits live at lane bits {0,1,4}
  #pragma unroll
  for (int t = 0; t < 9; ++t) {
    l0[t] += __shfl_xor(l0[t], 1, 64);
    l1[t] += __shfl_xor(l1[t], 1, 64);
  }
  #pragma unroll
  for (int t = 0; t < 9; ++t) {
    l0[t] += __shfl_xor(l0[t], 2, 64);
    l1[t] += __shfl_xor(l1[t], 2, 64);
  }
  #pragma unroll
  for (int t = 0; t < 9; ++t) {
    l0[t] += __shfl_xor(l0[t], 16, 64);
    l1[t] += __shfl_xor(l1[t], 16, 64);
  }

  // ---- Phase 2: mask + softmax over 9 (padded keys keep logit 0 in denom) ----
  float msk[9];
  #pragma unroll
  for (int r = 0; r < 3; ++r) {
    msk[r*3+0] = rowm[r] * mL;
    msk[r*3+1] = rowm[r];
    msk[r*3+2] = rowm[r] * mR;
  }
  float mx0 = -1e30f, mx1 = -1e30f;
  #pragma unroll
  for (int t = 0; t < 9; ++t) {
    l0[t] *= msk[t]; l1[t] *= msk[t];
    mx0 = fmaxf(mx0, l0[t]); mx1 = fmaxf(mx1, l1[t]);
  }
  float s0 = 0.0f, s1 = 0.0f;
  #pragma unroll
  for (int t = 0; t < 9; ++t) {
    l0[t] = __expf((l0[t] - mx0) * SCALE);
    l1[t] = __expf((l1[t] - mx1) * SCALE);
    s0 += l0[t]; s1 += l1[t];
  }
  const float r0 = 1.0f / s0, r1 = 1.0f / s1;
  #pragma unroll
  for (int t = 0; t < 9; ++t) {
    l0[t] *= r0 * msk[t];   // fold V zero-pad into weights
    l1[t] *= r1 * msk[t];
  }

  // ---- Phase 3: PV over this thread's 4 channels, from LDS ----
  float o0[4] = {0, 0, 0, 0}, o1[4] = {0, 0, 0, 0};
  #pragma unroll
  for (int r = 0; r < 3; ++r) {
    #pragma unroll
    for (int ci = 0; ci < 4; ++ci) {
      const float* vc = vbuf + (cg * 4 + ci) * CHP + r * 64;
      const float2 vL = *(const float2*)(vc + txL);
      const float2 vC = *(const float2*)(vc + txC);
      const float2 vR = *(const float2*)(vc + txR);
      o0[ci] = fmaf(l0[r*3+0], vL.x, o0[ci]);
      o0[ci] = fmaf(l0[r*3+1], vC.x, o0[ci]);
      o0[ci] = fmaf(l0[r*3+2], vR.x, o0[ci]);
      o1[ci] = fmaf(l1[r*3+0], vL.y, o1[ci]);
      o1[ci] = fmaf(l1[r*3+1], vC.y, o1[ci]);
      o1[ci] = fmaf(l1[r*3+2], vR.y, o1[ci]);
    }
  }

  // ---- Stores: same address set per wave as R6 (full 128B lines) ----
  float* ob = out + ((size_t)(b * 64 + h) * 64 + px0) * 128 + head * 32 + cg * 4;
  *(float4*)(ob)       = make_float4(o0[0], o0[1], o0[2], o0[3]);
  *(float4*)(ob + 128) = make_float4(o1[0], o1[1], o1[2], o1[3]);
}
} // namespace

extern "C" void kernel_launch(void* const* d_in, const int* in_sizes, int n_in,
                              void* d_out, int out_size, void* d_ws, size_t ws_size,
                              hipStream_t stream) {
  const float* q = (const float*)d_in[0];
  const float* k = (const float*)d_in[1];
  const float* v = (const float*)d_in[2];
  float* o = (float*)d_out;
  // 16 b x 4 heads x 64 rows = 4096 blocks
  dilate_attn<<<dim3(4096), dim3(256), 0, stream>>>(q, k, v, o);
}